// Round 13
// baseline (615.148 us; speedup 1.0000x reference)
//
#include <hip/hip_runtime.h>
#include <math.h>

#define DEPTH 18
#define NINT ((1 << (DEPTH - 1)) - 1)      // internal nodes = 131071
#define LEAF_OFF ((1 << (DEPTH - 2)) - 1)  // first level-16 node = 65535
#define NVOCAB 50000
#define SAW 520                             // sA row stride: [x|hs|h1|h2] + pad
#define KTS 9                               // Bfrag ktile stride (8 used + 1 pad; kills pow2 aliasing — r10 A/B: 70->55us)

typedef unsigned short bf16raw;
typedef __bf16 bf16x8 __attribute__((ext_vector_type(8)));
typedef float f32x4 __attribute__((ext_vector_type(4)));
typedef short short8 __attribute__((ext_vector_type(8)));

__device__ __forceinline__ float sigm(float x) { return 1.0f / (1.0f + __expf(-x)); }
// NaN-safe fast tanh (saturates correctly at +-inf).
__device__ __forceinline__ float fast_tanh(float x) {
    float t = __expf(2.0f * x);
    return 1.0f - 2.0f / (t + 1.0f);
}

__device__ __forceinline__ float bf2f(bf16raw u) {
    union { unsigned int i; float f; } v;
    v.i = ((unsigned int)u) << 16;
    return v.f;
}
__device__ __forceinline__ bf16raw f2bf(float f) {
    union { float f; unsigned int i; } v;
    v.f = f;
    unsigned int r = v.i + 0x7FFFu + ((v.i >> 16) & 1u);  // RNE
    return (bf16raw)(r >> 16);
}

#define SB() __builtin_amdgcn_sched_barrier(0)

// ---------------------------------------------------------------------------
__global__ __launch_bounds__(256) void k_prep_embeds(const float* __restrict__ src,
                                                     bf16raw* __restrict__ dst, int n4)
{
    int i = blockIdx.x * blockDim.x + threadIdx.x;
    if (i < n4) {
        float4 v = ((const float4*)src)[i];
        ushort4 o;
        o.x = f2bf(v.x); o.y = f2bf(v.y); o.z = f2bf(v.z); o.w = f2bf(v.w);
        ((ushort4*)dst)[i] = o;
    }
}

// ---------------------------------------------------------------------------
// Bfrag: fragment-linear, dedup'd B.  Gates: 0=i, 1=u, 2=o, 3=f; each gate
// [Wx|Wh], K=256 (8 ktiles, stride KTS=9 to avoid power-of-2 strides).
//   Bfrag[(((gate*8+coltile)*KTS+ktile)*64 + lane)*8 + e]
//   coltile=col>>4, lane=((k>>3)&3)*16+(col&15), ktile=k>>5, e=k&7.
// Blocks 512..527 build WoutFrag: 16-col padded WoutT fragment tile
// (cols 0..4 = Wout rows, 5..15 zero), K=128 (4 ktiles):
//   WoutFrag[((kt*64 + ((k>>3)&3)*16 + col)*8 + (k&7)] = Wout[col*128+k].
// ---------------------------------------------------------------------------
__global__ __launch_bounds__(128) void k_prep_bcat(
    const float* __restrict__ Wix, const float* __restrict__ bix,
    const float* __restrict__ Wih, const float* __restrict__ bih,
    const float* __restrict__ Wfx, const float* __restrict__ bfx,
    const float* __restrict__ Wfh, const float* __restrict__ bfh,
    const float* __restrict__ Wox, const float* __restrict__ box_,
    const float* __restrict__ Woh, const float* __restrict__ boh,
    const float* __restrict__ Wux, const float* __restrict__ bux,
    const float* __restrict__ Wuh, const float* __restrict__ buh,
    const float* __restrict__ Wout,
    bf16raw* __restrict__ Bfrag, bf16raw* __restrict__ WoutFrag,
    float* __restrict__ bias_cat)
{
    const int j = blockIdx.x;        // 0..511 = gate*128 + col; 512..527 = WoutFrag col
    if (j >= 512) {
        const int col = j - 512;     // 0..15
        for (int k = threadIdx.x; k < 128; k += blockDim.x) {
            float v = (col < 5) ? Wout[col * 128 + k] : 0.f;
            WoutFrag[((k >> 5) * 64 + ((k >> 3) & 3) * 16 + col) * 8 + (k & 7)] = f2bf(v);
        }
        return;
    }
    const int gate = j >> 7, jj = j & 127;
    const float *Wx, *Wh, *bx, *bh;
    switch (gate) {
        case 0: Wx = Wix; Wh = Wih; bx = bix;  bh = bih; break;
        case 1: Wx = Wux; Wh = Wuh; bx = bux;  bh = buh; break;
        case 2: Wx = Wox; Wh = Woh; bx = box_; bh = boh; break;
        default: Wx = Wfx; Wh = Wfh; bx = bfx; bh = bfh; break;
    }
    const int coltile = (j >> 4) & 7, lr = j & 15;
    for (int k = threadIdx.x; k < 256; k += blockDim.x) {
        float v = (k < 128) ? Wx[jj * 128 + k] : Wh[jj * 128 + (k - 128)];
        const int idx = (((gate * 8 + coltile) * KTS + (k >> 5)) * 64
                         + ((k >> 3) & 3) * 16 + lr) * 8 + (k & 7);
        Bfrag[idx] = f2bf(v);
    }
    if (threadIdx.x == 0) bias_cat[j] = bx[jj] + bh[jj];
}

// ---------------------------------------------------------------------------
// k_leafpre burst helpers (64-row variant: acc[2][4], x-part ktiles 0..3).
// ---------------------------------------------------------------------------
template<int CB>
__device__ __forceinline__ void lp_burst(const bf16raw* __restrict__ bfbase, int wcol,
                                         bf16x8 (&bb)[16])
{
#pragma unroll
    for (int kt = 0; kt < 4; ++kt)
#pragma unroll
        for (int j = 0; j < 4; ++j)
            bb[kt * 4 + j] = *(const bf16x8*)(bfbase +
                    (long)(((CB * 8 + (wcol >> 4) + j) * KTS + kt) * 512));
}

__device__ __forceinline__ void lp_mfma_all(const bf16raw* __restrict__ sA, int wrow,
                                            int lrow, int lquad,
                                            bf16x8 (&bb)[16], f32x4 (&acc)[2][4])
{
#pragma unroll
    for (int kt = 0; kt < 4; ++kt) {
        bf16x8 af[2];
#pragma unroll
        for (int i = 0; i < 2; ++i)
            af[i] = *(const bf16x8*)&sA[(wrow + i * 16 + lrow) * 136 + kt * 32 + lquad * 8];
#pragma unroll
        for (int i = 0; i < 2; ++i)
#pragma unroll
            for (int j = 0; j < 4; ++j)
                acc[i][j] = __builtin_amdgcn_mfma_f32_16x16x32_bf16(af[i], bb[kt * 4 + j], acc[i][j], 0, 0, 0);
    }
}

template<int CB>
__device__ __forceinline__ void lp_rungemm(const bf16raw* __restrict__ sA,
                                           const bf16raw* __restrict__ bfbase,
                                           int wrow, int wcol, int lrow, int lquad,
                                           f32x4 (&acc)[2][4])
{
#pragma unroll
    for (int i = 0; i < 2; i++)
#pragma unroll
        for (int j = 0; j < 4; j++) acc[i][j] = (f32x4){0.f, 0.f, 0.f, 0.f};
    bf16x8 bb[16];
    lp_burst<CB>(bfbase, wcol, bb);
    SB();
    lp_mfma_all(sA, wrow, lrow, lquad, bb, acc);
}

// ---------------------------------------------------------------------------
// k_level half-burst helpers.  Wave w: coltiles w*2, w*2+1.
// ---------------------------------------------------------------------------
template<int G, int H>
__device__ __forceinline__ void load8(const bf16raw* __restrict__ bfbase, int w,
                                      bf16x8 (&bb)[8])
{
#pragma unroll
    for (int kt2 = 0; kt2 < 4; ++kt2)
#pragma unroll
        for (int jj = 0; jj < 2; ++jj)
            bb[kt2 * 2 + jj] = *(const bf16x8*)(bfbase +
                    (long)(((G * 8 + w * 2 + jj) * KTS + H * 4 + kt2) * 512));
}

// 4-ktile MFMA group from A-ktile base AB (x=0, hs=4, h1=8, h2=12).
template<int AB>
__device__ __forceinline__ void mfma4k(const bf16raw* __restrict__ sA, int lrow, int lquad,
                                       bf16x8 (&bb)[8], f32x4 (&acc)[2][2])
{
#pragma unroll
    for (int kt2 = 0; kt2 < 4; ++kt2) {
        bf16x8 af[2];
#pragma unroll
        for (int i = 0; i < 2; ++i)
            af[i] = *(const bf16x8*)&sA[(i * 16 + lrow) * SAW + (AB + kt2) * 32 + lquad * 8];
#pragma unroll
        for (int jj = 0; jj < 2; ++jj)
#pragma unroll
            for (int i = 0; i < 2; ++i)
                acc[i][jj] = __builtin_amdgcn_mfma_f32_16x16x32_bf16(af[i], bb[kt2 * 2 + jj], acc[i][jj], 0, 0, 0);
    }
}

// ---------------------------------------------------------------------------
// k_leafpre: per-vocab leaf tables (h, c, logits, lse).  64 rows/block (r10).
// ---------------------------------------------------------------------------
__global__ __launch_bounds__(256, 3) void k_leafpre(
    const bf16raw* __restrict__ embeds_bf,
    const bf16raw* __restrict__ Bfrag, const float* __restrict__ bias_cat,
    const float* __restrict__ Wout, const float* __restrict__ bout,
    bf16raw* __restrict__ hc_leaf, float* __restrict__ lossv6, int nvtot)
{
    const int vbase = blockIdx.x * 64;
    int nv = nvtot - vbase;
    if (nv > 64) nv = 64;
    if (nv <= 0) return;

    __shared__ __align__(16) bf16raw sA[64 * 136];
    __shared__ __align__(16) bf16raw sT[64 * 136];
    __shared__ float sWout[5 * 128];

    const int t = threadIdx.x;
    for (int i = t; i < 640; i += 256) sWout[i] = Wout[i];

    // ---- stage A: 4 threads/row x 32 elems ----
    {
        const int row = t >> 2;              // 0..63
        const int co = (t & 3) * 32;
        const int arow = (row < nv) ? row : 0;
        const bf16raw* ax = embeds_bf + (long)(vbase + arow) * 128;
        *(short8*)&sA[row * 136 + co]      = *(const short8*)(ax + co);
        *(short8*)&sA[row * 136 + co + 8]  = *(const short8*)(ax + co + 8);
        *(short8*)&sA[row * 136 + co + 16] = *(const short8*)(ax + co + 16);
        *(short8*)&sA[row * 136 + co + 24] = *(const short8*)(ax + co + 24);
    }

    const int lane = t & 63;
    const int w = t >> 6;
    const int wrow = (w & 1) * 32;
    const int wcol = (w >> 1) * 64;
    const int lrow = lane & 15;
    const int lquad = lane >> 4;

    __syncthreads();

    const bf16raw* bfbase = Bfrag + (long)lane * 8;

    float tval[2][4][4];
    f32x4 acc[2][4];

    // ---- i gate ----
    lp_rungemm<0>(sA, bfbase, wrow, wcol, lrow, lquad, acc);
#pragma unroll
    for (int i = 0; i < 2; i++)
#pragma unroll
        for (int jj = 0; jj < 4; jj++) {
            const float b = bias_cat[wcol + jj * 16 + lrow];
#pragma unroll
            for (int r = 0; r < 4; r++) tval[i][jj][r] = sigm(acc[i][jj][r] + b);
        }
    // ---- u gate: tval = c = i*u ----
    lp_rungemm<1>(sA, bfbase, wrow, wcol, lrow, lquad, acc);
#pragma unroll
    for (int i = 0; i < 2; i++)
#pragma unroll
        for (int jj = 0; jj < 4; jj++) {
            const float b = bias_cat[128 + wcol + jj * 16 + lrow];
#pragma unroll
            for (int r = 0; r < 4; r++) tval[i][jj][r] *= fast_tanh(acc[i][jj][r] + b);
        }
    // write c tile, keep tanh(c) in regs
#pragma unroll
    for (int i = 0; i < 2; i++)
#pragma unroll
        for (int jj = 0; jj < 4; jj++)
#pragma unroll
            for (int r = 0; r < 4; r++) {
                const int m = wrow + i * 16 + lquad * 4 + r;
                const int j = wcol + jj * 16 + lrow;
                sT[m * 136 + j] = f2bf(tval[i][jj][r]);
            }
#pragma unroll
    for (int i = 0; i < 2; i++)
#pragma unroll
        for (int jj = 0; jj < 4; jj++)
#pragma unroll
            for (int r = 0; r < 4; r++) tval[i][jj][r] = fast_tanh(tval[i][jj][r]);
    __syncthreads();
    // flush c
#pragma unroll
    for (int s = 0; s < 4; ++s) {
        int ci = t + 256 * s;
        int row = ci >> 4, c8 = (ci & 15) * 8;
        if (row < nv)
            *(short8*)(hc_leaf + (long)(vbase + row) * 256 + 128 + c8) = *(const short8*)&sT[row * 136 + c8];
    }
    // ---- o gate: h = sigm(o)*tanh(c) ----
    lp_rungemm<2>(sA, bfbase, wrow, wcol, lrow, lquad, acc);
    __syncthreads();
#pragma unroll
    for (int i = 0; i < 2; i++)
#pragma unroll
        for (int jj = 0; jj < 4; jj++) {
            const float b = bias_cat[256 + wcol + jj * 16 + lrow];
#pragma unroll
            for (int r = 0; r < 4; r++) {
                const int m = wrow + i * 16 + lquad * 4 + r;
                const int j = wcol + jj * 16 + lrow;
                sT[m * 136 + j] = f2bf(sigm(acc[i][jj][r] + b) * tval[i][jj][r]);
            }
        }
    __syncthreads();
    // flush h
#pragma unroll
    for (int s = 0; s < 4; ++s) {
        int ci = t + 256 * s;
        int row = ci >> 4, c8 = (ci & 15) * 8;
        if (row < nv)
            *(short8*)(hc_leaf + (long)(vbase + row) * 256 + c8) = *(const short8*)&sT[row * 136 + c8];
    }
    // logits + lse: 4 threads/row
    {
        const int row = t >> 2, q = t & 3;
        float p[5] = {0.f, 0.f, 0.f, 0.f, 0.f};
        for (int k0 = 0; k0 < 32; ++k0) {
            const int k = q * 32 + k0;
            float hv = bf2f(sT[row * 136 + k]);
#pragma unroll
            for (int l = 0; l < 5; l++) p[l] += hv * sWout[l * 128 + k];
        }
#pragma unroll
        for (int l = 0; l < 5; l++) {
            p[l] += __shfl_down(p[l], 2);
            p[l] += __shfl_down(p[l], 1);
        }
        if (q == 0 && row < nv) {
            float lg[5], mx = -1e30f;
#pragma unroll
            for (int l = 0; l < 5; l++) {
                lg[l] = p[l] + bout[l];
                mx = fmaxf(mx, lg[l]);
            }
            float se = 0.f;
#pragma unroll
            for (int l = 0; l < 5; l++) se += __expf(lg[l] - mx);
            float lse = __logf(se) + mx;
            float* dst = lossv6 + (long)(vbase + row) * 6;
#pragma unroll
            for (int l = 0; l < 5; l++) dst[l] = lg[l];
            dst[5] = lse;
        }
    }
}

// ---------------------------------------------------------------------------
// k_level32 (r13): one 32-node chunk, fused loss.
//  - children c: per-thread REGISTER gathers issued before the barrier
//    (latency hides under GEMM) — no sCT staging, no fold-time LDS reads.
//  - output c/h tile UNIONED with the dead sA region after the GEMM:
//    LDS 50.7 -> 33.3KB => 4 blocks/CU (was 3).
//  - fused logits (1 small MFMA pass vs WoutFrag, wave 0) + lse + loss
//    atomicAdd + root output: k_loss kernel eliminated.
// ---------------------------------------------------------------------------
__global__ __launch_bounds__(256, 4) void k_level32(
    const bf16raw* __restrict__ embeds_bf, const int* __restrict__ words,
    const int* __restrict__ labels,
    bf16raw* __restrict__ h_all, bf16raw* __restrict__ c_all,
    const bf16raw* __restrict__ hc_leaf, const float* __restrict__ lossv6,
    const bf16raw* __restrict__ Bfrag, const bf16raw* __restrict__ WoutFrag,
    const float* __restrict__ bias_cat, const float* __restrict__ bout,
    float* __restrict__ partials, float* __restrict__ out,
    int off, int nm, int leafkids, int isroot)
{
    __shared__ __align__(16) union {
        bf16raw a[32 * SAW];                               // GEMM A phase
        struct { bf16raw ct[64 * 136]; float lg[32 * 5]; } e;  // epilogue
    } sh;

    const int t = threadIdx.x;
    const int m0 = blockIdx.x * 32;
    const int lane = t & 63;
    const int w = t >> 6;
    const int lrow = lane & 15;
    const int lquad = lane >> 4;

    // ---- stage A tile [x|hs|h1|h2]: 8 threads/row ----
    {
        const int row = t >> 3;
        const int co = (t & 7) * 8;
        int mm = m0 + row; if (mm >= nm) mm = nm - 1;
        const long g = (long)off + mm;
        const bf16raw* px = embeds_bf + (long)words[g] * 128;
        const bf16raw *p1, *p2;
        if (leafkids) {
            p1 = hc_leaf + (long)words[2 * g + 1] * 256;
            p2 = hc_leaf + (long)words[2 * g + 2] * 256;
        } else {
            p1 = h_all + (2 * g + 1) * 128;
            p2 = h_all + (2 * g + 2) * 128;
        }
        short8 vx0 = *(const short8*)(px + co);
        short8 vx1 = *(const short8*)(px + 64 + co);
        short8 h10 = *(const short8*)(p1 + co);
        short8 h11 = *(const short8*)(p1 + 64 + co);
        short8 h20 = *(const short8*)(p2 + co);
        short8 h21 = *(const short8*)(p2 + 64 + co);
        short8 hs0, hs1;
#pragma unroll
        for (int e = 0; e < 8; ++e) {
            hs0[e] = (short)f2bf(bf2f((bf16raw)(unsigned short)h10[e]) +
                                 bf2f((bf16raw)(unsigned short)h20[e]));
            hs1[e] = (short)f2bf(bf2f((bf16raw)(unsigned short)h11[e]) +
                                 bf2f((bf16raw)(unsigned short)h21[e]));
        }
        *(short8*)&sh.a[row * SAW + co]        = vx0;
        *(short8*)&sh.a[row * SAW + 64 + co]   = vx1;
        *(short8*)&sh.a[row * SAW + 128 + co]  = hs0;
        *(short8*)&sh.a[row * SAW + 192 + co]  = hs1;
        *(short8*)&sh.a[row * SAW + 256 + co]  = h10;
        *(short8*)&sh.a[row * SAW + 320 + co]  = h11;
        *(short8*)&sh.a[row * SAW + 384 + co]  = h20;
        *(short8*)&sh.a[row * SAW + 448 + co]  = h21;
    }

    // ---- children c: per-thread register gathers (latency hides under GEMM) ----
    bf16raw c1r[2][2][4], c2r[2][2][4];
#pragma unroll
    for (int i = 0; i < 2; ++i)
#pragma unroll
        for (int r = 0; r < 4; ++r) {
            int mm = m0 + i * 16 + lquad * 4 + r;
            if (mm >= nm) mm = nm - 1;
            const long g = (long)off + mm;
            const bf16raw *s1, *s2;
            if (leafkids) {
                s1 = hc_leaf + (long)words[2 * g + 1] * 256 + 128;
                s2 = hc_leaf + (long)words[2 * g + 2] * 256 + 128;
            } else {
                s1 = c_all + (2 * g + 1) * 128;
                s2 = c_all + (2 * g + 2) * 128;
            }
#pragma unroll
            for (int jj = 0; jj < 2; ++jj) {
                const int j = w * 32 + jj * 16 + lrow;
                c1r[i][jj][r] = s1[j];
                c2r[i][jj][r] = s2[j];
            }
        }

    // bias preload (gate order 0=i,1=u,2=o,3=f)
    float bias[4][2];
#pragma unroll
    for (int g = 0; g < 4; ++g)
#pragma unroll
        for (int jj = 0; jj < 2; ++jj)
            bias[g][jj] = bias_cat[g * 128 + w * 32 + jj * 16 + lrow];

    __syncthreads();   // A tile staged

    const bf16raw* bfbase = Bfrag + (long)lane * 8;

    f32x4 acc[2][2];
    f32x4 fx[2][2];      // Wfx·x stash (shared by f1/f2)
    float si[2][2][4];   // sigm(i) stash
    float cc[2][2][4];   // running c
    float hh[2][2][4];   // final h
    bf16x8 bbA[8], bbB[8];

#define ZACC() { _Pragma("unroll") for (int i_ = 0; i_ < 2; ++i_) \
                 _Pragma("unroll") for (int j_ = 0; j_ < 2; ++j_) \
                     acc[i_][j_] = (f32x4){0.f, 0.f, 0.f, 0.f}; }

    load8<0, 0>(bfbase, w, bbA);
    load8<0, 1>(bfbase, w, bbB);
    SB();
    ZACC();
    mfma4k<0>(sh.a, lrow, lquad, bbA, acc); SB();
    load8<1, 0>(bfbase, w, bbA); SB();
    mfma4k<4>(sh.a, lrow, lquad, bbB, acc); SB();
    load8<1, 1>(bfbase, w, bbB); SB();
    // fold i
#pragma unroll
    for (int i = 0; i < 2; ++i)
#pragma unroll
        for (int jj = 0; jj < 2; ++jj)
#pragma unroll
            for (int r = 0; r < 4; ++r)
                si[i][jj][r] = sigm(acc[i][jj][r] + bias[0][jj]);
    ZACC();
    mfma4k<0>(sh.a, lrow, lquad, bbA, acc); SB();
    load8<3, 0>(bfbase, w, bbA); SB();          // f-gate x-part B
    mfma4k<4>(sh.a, lrow, lquad, bbB, acc); SB();
    load8<3, 1>(bfbase, w, bbB); SB();          // f-gate h-part B
    // fold u: cc = sigm(i) * tanh(u)
#pragma unroll
    for (int i = 0; i < 2; ++i)
#pragma unroll
        for (int jj = 0; jj < 2; ++jj)
#pragma unroll
            for (int r = 0; r < 4; ++r)
                cc[i][jj][r] = si[i][jj][r] * fast_tanh(acc[i][jj][r] + bias[1][jj]);
    // fx = Wfx·x (once)
    ZACC();
    mfma4k<0>(sh.a, lrow, lquad, bbA, acc);
    SB();
#pragma unroll
    for (int i = 0; i < 2; ++i)
#pragma unroll
        for (int jj = 0; jj < 2; ++jj) fx[i][jj] = acc[i][jj];
    // f1 = fx + Wfh·h1
    mfma4k<8>(sh.a, lrow, lquad, bbB, acc);
    SB();
    load8<2, 0>(bfbase, w, bbA);                // o-gate x B (overlaps fold)
    SB();
    // fold f1: cc += sigm(f1) * c1 (register child values)
#pragma unroll
    for (int i = 0; i < 2; ++i)
#pragma unroll
        for (int jj = 0; jj < 2; ++jj)
#pragma unroll
            for (int r = 0; r < 4; ++r)
                cc[i][jj][r] += sigm(acc[i][jj][r] + bias[3][jj]) * bf2f(c1r[i][jj][r]);
    // f2 = fx + Wfh·h2
#pragma unroll
    for (int i = 0; i < 2; ++i)
#pragma unroll
        for (int jj = 0; jj < 2; ++jj) acc[i][jj] = fx[i][jj];
    mfma4k<12>(sh.a, lrow, lquad, bbB, acc);
    SB();
    load8<2, 1>(bfbase, w, bbB);                // o-gate h B
    SB();
    // fold f2: cc += sigm(f2) * c2
#pragma unroll
    for (int i = 0; i < 2; ++i)
#pragma unroll
        for (int jj = 0; jj < 2; ++jj)
#pragma unroll
            for (int r = 0; r < 4; ++r)
                cc[i][jj][r] += sigm(acc[i][jj][r] + bias[3][jj]) * bf2f(c2r[i][jj][r]);
    ZACC();
    mfma4k<0>(sh.a, lrow, lquad, bbA, acc);
    mfma4k<4>(sh.a, lrow, lquad, bbB, acc);
    SB();
    // fold o: hh = sigm(o) * tanh(cc)
#pragma unroll
    for (int i = 0; i < 2; ++i)
#pragma unroll
        for (int jj = 0; jj < 2; ++jj)
#pragma unroll
            for (int r = 0; r < 4; ++r)
                hh[i][jj][r] = sigm(acc[i][jj][r] + bias[2][jj]) * fast_tanh(cc[i][jj][r]);
#undef ZACC

    __syncthreads();   // all sh.a reads done; safe to reuse as sh.e

    // ---- write c (rows 0..31) / h (rows 32..63) tiles ----
#pragma unroll
    for (int i = 0; i < 2; ++i)
#pragma unroll
        for (int jj = 0; jj < 2; ++jj) {
            const int j = w * 32 + jj * 16 + lrow;
#pragma unroll
            for (int r = 0; r < 4; ++r) {
                const int m = i * 16 + lquad * 4 + r;
                sh.e.ct[m * 136 + j] = f2bf(cc[i][jj][r]);
                sh.e.ct[(32 + m) * 136 + j] = f2bf(hh[i][jj][r]);
            }
        }
    __syncthreads();

    // ---- coalesced flush ----
#pragma unroll
    for (int q = 0; q < 4; ++q) {
        int ci = t + 256 * q;
        int row = ci >> 4;
        int c8 = (ci & 15) * 8;
        int m = row & 31;
        if (m0 + m < nm) {
            bf16raw* dst = (row < 32) ? c_all : h_all;
            *(short8*)(dst + ((long)off + m0 + m) * 128 + c8) = *(const short8*)&sh.e.ct[row * 136 + c8];
        }
    }

    // ---- fused logits: wave 0, one MFMA pass vs WoutFrag ----
    if (w == 0) {
        f32x4 lacc[2];
        lacc[0] = (f32x4){0.f, 0.f, 0.f, 0.f};
        lacc[1] = (f32x4){0.f, 0.f, 0.f, 0.f};
#pragma unroll
        for (int kt = 0; kt < 4; ++kt) {
            bf16x8 bfr = *(const bf16x8*)(WoutFrag + (long)((kt * 64 + lane) * 8));
#pragma unroll
            for (int i = 0; i < 2; ++i) {
                bf16x8 af = *(const bf16x8*)&sh.e.ct[(32 + i * 16 + lrow) * 136 + kt * 32 + lquad * 8];
                lacc[i] = __builtin_amdgcn_mfma_f32_16x16x32_bf16(af, bfr, lacc[i], 0, 0, 0);
            }
        }
        if (lrow < 5) {
            const float bl = bout[lrow];
#pragma unroll
            for (int i = 0; i < 2; ++i)
#pragma unroll
                for (int r = 0; r < 4; ++r)
                    sh.e.lg[(i * 16 + lquad * 4 + r) * 5 + lrow] = lacc[i][r] + bl;
        }
    }
    __syncthreads();

    // ---- lse + loss per node (32 threads) ----
    if (t < 32 && m0 + t < nm) {
        const long g = (long)off + m0 + t;
        float lgv[5], mx = -1e30f;
#pragma unroll
        for (int l = 0; l < 5; ++l) {
            lgv[l] = sh.e.lg[t * 5 + l];
            mx = fmaxf(mx, lgv[l]);
        }
        float se = 0.f;
#pragma unroll
        for (int l = 0; l < 5; ++l) se += __expf(lgv[l] - mx);
        float lse = __logf(se) + mx;
        float lossNode = lse - lgv[labels[g]];
        if (leafkids) {
            const float* lv1 = lossv6 + (long)words[2 * g + 1] * 6;
            const float* lv2 = lossv6 + (long)words[2 * g + 2] * 6;
            lossNode += (lv1[5] - lv1[labels[2 * g + 1]])
                      + (lv2[5] - lv2[labels[2 * g + 2]]);
        }
        atomicAdd(&partials[(int)(g & 1023)], lossNode);
        if (isroot && g == 0) {
#pragma unroll
            for (int l = 0; l < 5; ++l) out[l] = lgv[l] - lse;
        }
    }
}

__global__ __launch_bounds__(256) void k3_reduce(const float* __restrict__ partials,
                                                 float* __restrict__ out)
{
    const int t = threadIdx.x;
    float s = 0.f;
    for (int i = t; i < 1024; i += 256) s += partials[i];
#pragma unroll
    for (int d = 32; d > 0; d >>= 1) s += __shfl_down(s, d);
    __shared__ float red[4];
    if ((t & 63) == 0) red[t >> 6] = s;
    __syncthreads();
    if (t == 0) out[5] = red[0] + red[1] + red[2] + red[3];
}

// ---------------------------------------------------------------------------
extern "C" void kernel_launch(void* const* d_in, const int* in_sizes, int n_in,
                              void* d_out, int out_size, void* d_ws, size_t ws_size,
                              hipStream_t stream)
{
    const float* embeds = (const float*)d_in[0];
    const int* words = (const int*)d_in[1];
    const int* labels = (const int*)d_in[2];
    const float* Wix = (const float*)d_in[5],  *bix  = (const float*)d_in[6];
    const float* Wih = (const float*)d_in[7],  *bih  = (const float*)d_in[8];
    const float* Wfx = (const float*)d_in[9],  *bfx  = (const float*)d_in[10];
    const float* Wfh = (const float*)d_in[11], *bfh  = (const float*)d_in[12];
    const float* Wox = (const float*)d_in[13], *box_ = (const float*)d_in[14];
    const float* Woh = (const float*)d_in[15], *boh  = (const float*)d_in[16];
    const float* Wux = (const float*)d_in[17], *bux  = (const float*)d_in[18];
    const float* Wuh = (const float*)d_in[19], *buh  = (const float*)d_in[20];
    const float* Wout = (const float*)d_in[21], *bout = (const float*)d_in[22];
    float* out = (float*)d_out;

    char* ws = (char*)d_ws;
    const size_t treeElems = (size_t)NINT * 128;
    bf16raw* h_all = (bf16raw*)ws;
    bf16raw* c_all = h_all + treeElems;
    bf16raw* embeds_bf = c_all + treeElems;
    bf16raw* Bfrag = embeds_bf + (size_t)NVOCAB * 128;
    bf16raw* WoutFrag = Bfrag + 4 * 8 * KTS * 512;       // padded dedup B, then WoutT frag
    bf16raw* hc_leaf = WoutFrag + 4 * 64 * 8;
    float* lossv6 = (float*)(hc_leaf + (size_t)NVOCAB * 256);
    float* bias_cat = lossv6 + (size_t)NVOCAB * 6;
    float* partials = bias_cat + 512;

    k_prep_embeds<<<(NVOCAB * 128 / 4 + 255) / 256, 256, 0, stream>>>(
        embeds, embeds_bf, NVOCAB * 128 / 4);
    k_prep_bcat<<<528, 128, 0, stream>>>(Wix, bix, Wih, bih, Wfx, bfx, Wfh, bfh,
                                         Wox, box_, Woh, boh, Wux, bux, Wuh, buh,
                                         Wout, Bfrag, WoutFrag, bias_cat);
    hipMemsetAsync(partials, 0, 1024 * sizeof(float), stream);

    k_leafpre<<<(NVOCAB + 63) / 64, 256, 0, stream>>>(
        embeds_bf, Bfrag, bias_cat, Wout, bout, hc_leaf, lossv6, NVOCAB);

    for (int l = DEPTH - 2; l >= 0; --l) {
        const int n = 1 << l;
        k_level32<<<dim3((n + 31) / 32), 256, 0, stream>>>(
            embeds_bf, words, labels, h_all, c_all, hc_leaf, lossv6,
            Bfrag, WoutFrag, bias_cat, bout, partials, out,
            n - 1, n, (l == DEPTH - 2) ? 1 : 0, (l == 0) ? 1 : 0);
    }

    k3_reduce<<<1, 256, 0, stream>>>(partials, out);
}

// Round 14
// 371.389 us; speedup vs baseline: 1.6563x; 1.6563x over previous
//
#include <hip/hip_runtime.h>
#include <math.h>

#define DEPTH 18
#define NINT ((1 << (DEPTH - 1)) - 1)      // internal nodes = 131071
#define LEAF_OFF ((1 << (DEPTH - 2)) - 1)  // first level-16 node = 65535
#define NVOCAB 50000
#define SAW 520                             // sA row stride: [x|hs|h1|h2] + pad
#define KTS 9                               // Bfrag ktile stride (8 used + 1 pad; kills pow2 aliasing — r10 A/B: 70->55us)

typedef unsigned short bf16raw;
typedef __bf16 bf16x8 __attribute__((ext_vector_type(8)));
typedef float f32x4 __attribute__((ext_vector_type(4)));
typedef short short8 __attribute__((ext_vector_type(8)));

__device__ __forceinline__ float sigm(float x) { return 1.0f / (1.0f + __expf(-x)); }
// NaN-safe fast tanh (saturates correctly at +-inf).
__device__ __forceinline__ float fast_tanh(float x) {
    float t = __expf(2.0f * x);
    return 1.0f - 2.0f / (t + 1.0f);
}

__device__ __forceinline__ float bf2f(bf16raw u) {
    union { unsigned int i; float f; } v;
    v.i = ((unsigned int)u) << 16;
    return v.f;
}
__device__ __forceinline__ bf16raw f2bf(float f) {
    union { float f; unsigned int i; } v;
    v.f = f;
    unsigned int r = v.i + 0x7FFFu + ((v.i >> 16) & 1u);  // RNE
    return (bf16raw)(r >> 16);
}

#define SB() __builtin_amdgcn_sched_barrier(0)

// ---------------------------------------------------------------------------
__global__ __launch_bounds__(256) void k_prep_embeds(const float* __restrict__ src,
                                                     bf16raw* __restrict__ dst, int n4)
{
    int i = blockIdx.x * blockDim.x + threadIdx.x;
    if (i < n4) {
        float4 v = ((const float4*)src)[i];
        ushort4 o;
        o.x = f2bf(v.x); o.y = f2bf(v.y); o.z = f2bf(v.z); o.w = f2bf(v.w);
        ((ushort4*)dst)[i] = o;
    }
}

// ---------------------------------------------------------------------------
// Bfrag: fragment-linear, dedup'd B.  Gates: 0=i, 1=u, 2=o, 3=f; each gate
// [Wx|Wh], K=256 (8 ktiles, stride KTS=9 to avoid power-of-2 strides).
//   Bfrag[(((gate*8+coltile)*KTS+ktile)*64 + lane)*8 + e]
// Blocks 512..527 build WoutFrag (validated r13): 16-col padded WoutT
// fragment tile (cols 0..4 = Wout rows, 5..15 zero), K=128 (4 ktiles).
// ---------------------------------------------------------------------------
__global__ __launch_bounds__(128) void k_prep_bcat(
    const float* __restrict__ Wix, const float* __restrict__ bix,
    const float* __restrict__ Wih, const float* __restrict__ bih,
    const float* __restrict__ Wfx, const float* __restrict__ bfx,
    const float* __restrict__ Wfh, const float* __restrict__ bfh,
    const float* __restrict__ Wox, const float* __restrict__ box_,
    const float* __restrict__ Woh, const float* __restrict__ boh,
    const float* __restrict__ Wux, const float* __restrict__ bux,
    const float* __restrict__ Wuh, const float* __restrict__ buh,
    const float* __restrict__ Wout,
    bf16raw* __restrict__ Bfrag, bf16raw* __restrict__ WoutFrag,
    float* __restrict__ bias_cat)
{
    const int j = blockIdx.x;        // 0..511 = gate*128 + col; 512..527 = WoutFrag col
    if (j >= 512) {
        const int col = j - 512;     // 0..15
        for (int k = threadIdx.x; k < 128; k += blockDim.x) {
            float v = (col < 5) ? Wout[col * 128 + k] : 0.f;
            WoutFrag[((k >> 5) * 64 + ((k >> 3) & 3) * 16 + col) * 8 + (k & 7)] = f2bf(v);
        }
        return;
    }
    const int gate = j >> 7, jj = j & 127;
    const float *Wx, *Wh, *bx, *bh;
    switch (gate) {
        case 0: Wx = Wix; Wh = Wih; bx = bix;  bh = bih; break;
        case 1: Wx = Wux; Wh = Wuh; bx = bux;  bh = buh; break;
        case 2: Wx = Wox; Wh = Woh; bx = box_; bh = boh; break;
        default: Wx = Wfx; Wh = Wfh; bx = bfx; bh = bfh; break;
    }
    const int coltile = (j >> 4) & 7, lr = j & 15;
    for (int k = threadIdx.x; k < 256; k += blockDim.x) {
        float v = (k < 128) ? Wx[jj * 128 + k] : Wh[jj * 128 + (k - 128)];
        const int idx = (((gate * 8 + coltile) * KTS + (k >> 5)) * 64
                         + ((k >> 3) & 3) * 16 + lr) * 8 + (k & 7);
        Bfrag[idx] = f2bf(v);
    }
    if (threadIdx.x == 0) bias_cat[j] = bx[jj] + bh[jj];
}

// ---------------------------------------------------------------------------
// k_leafpre burst helpers (64-row variant: acc[2][4], x-part ktiles 0..3).
// ---------------------------------------------------------------------------
template<int CB>
__device__ __forceinline__ void lp_burst(const bf16raw* __restrict__ bfbase, int wcol,
                                         bf16x8 (&bb)[16])
{
#pragma unroll
    for (int kt = 0; kt < 4; ++kt)
#pragma unroll
        for (int j = 0; j < 4; ++j)
            bb[kt * 4 + j] = *(const bf16x8*)(bfbase +
                    (long)(((CB * 8 + (wcol >> 4) + j) * KTS + kt) * 512));
}

__device__ __forceinline__ void lp_mfma_all(const bf16raw* __restrict__ sA, int wrow,
                                            int lrow, int lquad,
                                            bf16x8 (&bb)[16], f32x4 (&acc)[2][4])
{
#pragma unroll
    for (int kt = 0; kt < 4; ++kt) {
        bf16x8 af[2];
#pragma unroll
        for (int i = 0; i < 2; ++i)
            af[i] = *(const bf16x8*)&sA[(wrow + i * 16 + lrow) * 136 + kt * 32 + lquad * 8];
#pragma unroll
        for (int i = 0; i < 2; ++i)
#pragma unroll
            for (int j = 0; j < 4; ++j)
                acc[i][j] = __builtin_amdgcn_mfma_f32_16x16x32_bf16(af[i], bb[kt * 4 + j], acc[i][j], 0, 0, 0);
    }
}

template<int CB>
__device__ __forceinline__ void lp_rungemm(const bf16raw* __restrict__ sA,
                                           const bf16raw* __restrict__ bfbase,
                                           int wrow, int wcol, int lrow, int lquad,
                                           f32x4 (&acc)[2][4])
{
#pragma unroll
    for (int i = 0; i < 2; i++)
#pragma unroll
        for (int j = 0; j < 4; j++) acc[i][j] = (f32x4){0.f, 0.f, 0.f, 0.f};
    bf16x8 bb[16];
    lp_burst<CB>(bfbase, wcol, bb);
    SB();
    lp_mfma_all(sA, wrow, lrow, lquad, bb, acc);
}

// ---------------------------------------------------------------------------
// k_level half-burst helpers.  Wave w: coltiles w*2, w*2+1.
// ---------------------------------------------------------------------------
template<int G, int H>
__device__ __forceinline__ void load8(const bf16raw* __restrict__ bfbase, int w,
                                      bf16x8 (&bb)[8])
{
#pragma unroll
    for (int kt2 = 0; kt2 < 4; ++kt2)
#pragma unroll
        for (int jj = 0; jj < 2; ++jj)
            bb[kt2 * 2 + jj] = *(const bf16x8*)(bfbase +
                    (long)(((G * 8 + w * 2 + jj) * KTS + H * 4 + kt2) * 512));
}

// 4-ktile MFMA group from A-ktile base AB (x=0, hs=4, h1=8, h2=12).
template<int AB>
__device__ __forceinline__ void mfma4k(const bf16raw* __restrict__ sA, int lrow, int lquad,
                                       bf16x8 (&bb)[8], f32x4 (&acc)[2][2])
{
#pragma unroll
    for (int kt2 = 0; kt2 < 4; ++kt2) {
        bf16x8 af[2];
#pragma unroll
        for (int i = 0; i < 2; ++i)
            af[i] = *(const bf16x8*)&sA[(i * 16 + lrow) * SAW + (AB + kt2) * 32 + lquad * 8];
#pragma unroll
        for (int jj = 0; jj < 2; ++jj)
#pragma unroll
            for (int i = 0; i < 2; ++i)
                acc[i][jj] = __builtin_amdgcn_mfma_f32_16x16x32_bf16(af[i], bb[kt2 * 2 + jj], acc[i][jj], 0, 0, 0);
    }
}

// ---------------------------------------------------------------------------
// k_leafpre: per-vocab leaf tables (h, c, logits, lse).  64 rows/block (r10).
// ---------------------------------------------------------------------------
__global__ __launch_bounds__(256, 3) void k_leafpre(
    const bf16raw* __restrict__ embeds_bf,
    const bf16raw* __restrict__ Bfrag, const float* __restrict__ bias_cat,
    const float* __restrict__ Wout, const float* __restrict__ bout,
    bf16raw* __restrict__ hc_leaf, float* __restrict__ lossv6, int nvtot)
{
    const int vbase = blockIdx.x * 64;
    int nv = nvtot - vbase;
    if (nv > 64) nv = 64;
    if (nv <= 0) return;

    __shared__ __align__(16) bf16raw sA[64 * 136];
    __shared__ __align__(16) bf16raw sT[64 * 136];
    __shared__ float sWout[5 * 128];

    const int t = threadIdx.x;
    for (int i = t; i < 640; i += 256) sWout[i] = Wout[i];

    // ---- stage A: 4 threads/row x 32 elems ----
    {
        const int row = t >> 2;              // 0..63
        const int co = (t & 3) * 32;
        const int arow = (row < nv) ? row : 0;
        const bf16raw* ax = embeds_bf + (long)(vbase + arow) * 128;
        *(short8*)&sA[row * 136 + co]      = *(const short8*)(ax + co);
        *(short8*)&sA[row * 136 + co + 8]  = *(const short8*)(ax + co + 8);
        *(short8*)&sA[row * 136 + co + 16] = *(const short8*)(ax + co + 16);
        *(short8*)&sA[row * 136 + co + 24] = *(const short8*)(ax + co + 24);
    }

    const int lane = t & 63;
    const int w = t >> 6;
    const int wrow = (w & 1) * 32;
    const int wcol = (w >> 1) * 64;
    const int lrow = lane & 15;
    const int lquad = lane >> 4;

    __syncthreads();

    const bf16raw* bfbase = Bfrag + (long)lane * 8;

    float tval[2][4][4];
    f32x4 acc[2][4];

    // ---- i gate ----
    lp_rungemm<0>(sA, bfbase, wrow, wcol, lrow, lquad, acc);
#pragma unroll
    for (int i = 0; i < 2; i++)
#pragma unroll
        for (int jj = 0; jj < 4; jj++) {
            const float b = bias_cat[wcol + jj * 16 + lrow];
#pragma unroll
            for (int r = 0; r < 4; r++) tval[i][jj][r] = sigm(acc[i][jj][r] + b);
        }
    // ---- u gate: tval = c = i*u ----
    lp_rungemm<1>(sA, bfbase, wrow, wcol, lrow, lquad, acc);
#pragma unroll
    for (int i = 0; i < 2; i++)
#pragma unroll
        for (int jj = 0; jj < 4; jj++) {
            const float b = bias_cat[128 + wcol + jj * 16 + lrow];
#pragma unroll
            for (int r = 0; r < 4; r++) tval[i][jj][r] *= fast_tanh(acc[i][jj][r] + b);
        }
    // write c tile, keep tanh(c) in regs
#pragma unroll
    for (int i = 0; i < 2; i++)
#pragma unroll
        for (int jj = 0; jj < 4; jj++)
#pragma unroll
            for (int r = 0; r < 4; r++) {
                const int m = wrow + i * 16 + lquad * 4 + r;
                const int j = wcol + jj * 16 + lrow;
                sT[m * 136 + j] = f2bf(tval[i][jj][r]);
            }
#pragma unroll
    for (int i = 0; i < 2; i++)
#pragma unroll
        for (int jj = 0; jj < 4; jj++)
#pragma unroll
            for (int r = 0; r < 4; r++) tval[i][jj][r] = fast_tanh(tval[i][jj][r]);
    __syncthreads();
    // flush c
#pragma unroll
    for (int s = 0; s < 4; ++s) {
        int ci = t + 256 * s;
        int row = ci >> 4, c8 = (ci & 15) * 8;
        if (row < nv)
            *(short8*)(hc_leaf + (long)(vbase + row) * 256 + 128 + c8) = *(const short8*)&sT[row * 136 + c8];
    }
    // ---- o gate: h = sigm(o)*tanh(c) ----
    lp_rungemm<2>(sA, bfbase, wrow, wcol, lrow, lquad, acc);
    __syncthreads();
#pragma unroll
    for (int i = 0; i < 2; i++)
#pragma unroll
        for (int jj = 0; jj < 4; jj++) {
            const float b = bias_cat[256 + wcol + jj * 16 + lrow];
#pragma unroll
            for (int r = 0; r < 4; r++) {
                const int m = wrow + i * 16 + lquad * 4 + r;
                const int j = wcol + jj * 16 + lrow;
                sT[m * 136 + j] = f2bf(sigm(acc[i][jj][r] + b) * tval[i][jj][r]);
            }
        }
    __syncthreads();
    // flush h
#pragma unroll
    for (int s = 0; s < 4; ++s) {
        int ci = t + 256 * s;
        int row = ci >> 4, c8 = (ci & 15) * 8;
        if (row < nv)
            *(short8*)(hc_leaf + (long)(vbase + row) * 256 + c8) = *(const short8*)&sT[row * 136 + c8];
    }
    // logits + lse: 4 threads/row
    {
        const int row = t >> 2, q = t & 3;
        float p[5] = {0.f, 0.f, 0.f, 0.f, 0.f};
        for (int k0 = 0; k0 < 32; ++k0) {
            const int k = q * 32 + k0;
            float hv = bf2f(sT[row * 136 + k]);
#pragma unroll
            for (int l = 0; l < 5; l++) p[l] += hv * sWout[l * 128 + k];
        }
#pragma unroll
        for (int l = 0; l < 5; l++) {
            p[l] += __shfl_down(p[l], 2);
            p[l] += __shfl_down(p[l], 1);
        }
        if (q == 0 && row < nv) {
            float lg[5], mx = -1e30f;
#pragma unroll
            for (int l = 0; l < 5; l++) {
                lg[l] = p[l] + bout[l];
                mx = fmaxf(mx, lg[l]);
            }
            float se = 0.f;
#pragma unroll
            for (int l = 0; l < 5; l++) se += __expf(lg[l] - mx);
            float lse = __logf(se) + mx;
            float* dst = lossv6 + (long)(vbase + row) * 6;
#pragma unroll
            for (int l = 0; l < 5; l++) dst[l] = lg[l];
            dst[5] = lse;
        }
    }
}

// ---------------------------------------------------------------------------
// k_level32 (r14 = r12 body + validated fused-loss epilogue):
//  - LDS children staging (sCT), (256,3), fx-sharing — the proven 53.5us@L16
//    structure.  r13's (256,4)+register-gathers spilled (WRITE 33->140MB,
//    VGPR capped at 64): occupancy bought with spills is worthless.
//  - fused logits (wave-0 MFMA vs WoutFrag, layout validated r13) + lse +
//    loss atomicAdd + root output: k_loss kernel + its 33MB h_all re-read
//    eliminated.  +640B LDS -> 51.3KB, still 3 blocks/CU.
// ---------------------------------------------------------------------------
__global__ __launch_bounds__(256, 3) void k_level32(
    const bf16raw* __restrict__ embeds_bf, const int* __restrict__ words,
    const int* __restrict__ labels,
    bf16raw* __restrict__ h_all, bf16raw* __restrict__ c_all,
    const bf16raw* __restrict__ hc_leaf, const float* __restrict__ lossv6,
    const bf16raw* __restrict__ Bfrag, const bf16raw* __restrict__ WoutFrag,
    const float* __restrict__ bias_cat, const float* __restrict__ bout,
    float* __restrict__ partials, float* __restrict__ out,
    int off, int nm, int leafkids, int isroot)
{
    __shared__ __align__(16) bf16raw sA[32 * SAW];
    __shared__ __align__(16) bf16raw sCT[64 * 136];
    __shared__ float sLg[32 * 5];

    const int t = threadIdx.x;
    const int m0 = blockIdx.x * 32;

    // ---- stage A tile [x|hs|h1|h2]: 8 threads/row ----
    {
        const int row = t >> 3;
        const int co = (t & 7) * 8;
        int mm = m0 + row; if (mm >= nm) mm = nm - 1;
        const long g = (long)off + mm;
        const bf16raw* px = embeds_bf + (long)words[g] * 128;
        const bf16raw *p1, *p2;
        if (leafkids) {
            p1 = hc_leaf + (long)words[2 * g + 1] * 256;
            p2 = hc_leaf + (long)words[2 * g + 2] * 256;
        } else {
            p1 = h_all + (2 * g + 1) * 128;
            p2 = h_all + (2 * g + 2) * 128;
        }
        short8 vx0 = *(const short8*)(px + co);
        short8 vx1 = *(const short8*)(px + 64 + co);
        short8 h10 = *(const short8*)(p1 + co);
        short8 h11 = *(const short8*)(p1 + 64 + co);
        short8 h20 = *(const short8*)(p2 + co);
        short8 h21 = *(const short8*)(p2 + 64 + co);
        short8 hs0, hs1;
#pragma unroll
        for (int e = 0; e < 8; ++e) {
            hs0[e] = (short)f2bf(bf2f((bf16raw)(unsigned short)h10[e]) +
                                 bf2f((bf16raw)(unsigned short)h20[e]));
            hs1[e] = (short)f2bf(bf2f((bf16raw)(unsigned short)h11[e]) +
                                 bf2f((bf16raw)(unsigned short)h21[e]));
        }
        *(short8*)&sA[row * SAW + co]        = vx0;
        *(short8*)&sA[row * SAW + 64 + co]   = vx1;
        *(short8*)&sA[row * SAW + 128 + co]  = hs0;
        *(short8*)&sA[row * SAW + 192 + co]  = hs1;
        *(short8*)&sA[row * SAW + 256 + co]  = h10;
        *(short8*)&sA[row * SAW + 320 + co]  = h11;
        *(short8*)&sA[row * SAW + 384 + co]  = h20;
        *(short8*)&sA[row * SAW + 448 + co]  = h21;
    }
    // ---- stage children c: slot = 2*mlocal + childIdx ----
    {
        const int slot = t >> 2;
        const int cc8 = (t & 3) * 8;
        int mm = m0 + (slot >> 1); if (mm >= nm) mm = nm - 1;
        const long g = (long)off + mm;
        const long cg = 2 * g + 1 + (slot & 1);
        const bf16raw* pc = leafkids ? (hc_leaf + (long)words[cg] * 256 + 128)
                                     : (c_all + cg * 128);
#pragma unroll
        for (int s = 0; s < 4; ++s)
            *(short8*)&sCT[slot * 136 + s * 32 + cc8] = *(const short8*)(pc + s * 32 + cc8);
    }

    const int lane = t & 63;
    const int w = t >> 6;
    const int lrow = lane & 15;
    const int lquad = lane >> 4;

    // bias preload (gate order 0=i,1=u,2=o,3=f)
    float bias[4][2];
#pragma unroll
    for (int g = 0; g < 4; ++g)
#pragma unroll
        for (int jj = 0; jj < 2; ++jj)
            bias[g][jj] = bias_cat[g * 128 + w * 32 + jj * 16 + lrow];

    __syncthreads();   // A tile + children staged

    const bf16raw* bfbase = Bfrag + (long)lane * 8;

    f32x4 acc[2][2];
    f32x4 fx[2][2];      // Wfx·x stash (shared by f1/f2)
    float si[2][2][4];   // sigm(i) stash
    float cc[2][2][4];   // running c
    float hh[2][2][4];   // final h
    bf16x8 bbA[8], bbB[8];

#define ZACC() { _Pragma("unroll") for (int i_ = 0; i_ < 2; ++i_) \
                 _Pragma("unroll") for (int j_ = 0; j_ < 2; ++j_) \
                     acc[i_][j_] = (f32x4){0.f, 0.f, 0.f, 0.f}; }

    load8<0, 0>(bfbase, w, bbA);
    load8<0, 1>(bfbase, w, bbB);
    SB();
    ZACC();
    mfma4k<0>(sA, lrow, lquad, bbA, acc); SB();
    load8<1, 0>(bfbase, w, bbA); SB();
    mfma4k<4>(sA, lrow, lquad, bbB, acc); SB();
    load8<1, 1>(bfbase, w, bbB); SB();
    // fold i
#pragma unroll
    for (int i = 0; i < 2; ++i)
#pragma unroll
        for (int jj = 0; jj < 2; ++jj)
#pragma unroll
            for (int r = 0; r < 4; ++r)
                si[i][jj][r] = sigm(acc[i][jj][r] + bias[0][jj]);
    ZACC();
    mfma4k<0>(sA, lrow, lquad, bbA, acc); SB();
    load8<3, 0>(bfbase, w, bbA); SB();          // f-gate x-part B
    mfma4k<4>(sA, lrow, lquad, bbB, acc); SB();
    load8<3, 1>(bfbase, w, bbB); SB();          // f-gate h-part B
    // fold u: cc = sigm(i) * tanh(u)
#pragma unroll
    for (int i = 0; i < 2; ++i)
#pragma unroll
        for (int jj = 0; jj < 2; ++jj)
#pragma unroll
            for (int r = 0; r < 4; ++r)
                cc[i][jj][r] = si[i][jj][r] * fast_tanh(acc[i][jj][r] + bias[1][jj]);
    // fx = Wfx·x (once)
    ZACC();
    mfma4k<0>(sA, lrow, lquad, bbA, acc);
    SB();
#pragma unroll
    for (int i = 0; i < 2; ++i)
#pragma unroll
        for (int jj = 0; jj < 2; ++jj) fx[i][jj] = acc[i][jj];
    // f1 = fx + Wfh·h1
    mfma4k<8>(sA, lrow, lquad, bbB, acc);
    SB();
    load8<2, 0>(bfbase, w, bbA);                // o-gate x B (overlaps fold)
    SB();
    // fold f1: cc += sigm(f1) * c1
#pragma unroll
    for (int i = 0; i < 2; ++i)
#pragma unroll
        for (int jj = 0; jj < 2; ++jj) {
            const int j = w * 32 + jj * 16 + lrow;
#pragma unroll
            for (int r = 0; r < 4; ++r) {
                const int m = i * 16 + lquad * 4 + r;
                cc[i][jj][r] += sigm(acc[i][jj][r] + bias[3][jj]) * bf2f(sCT[(2 * m) * 136 + j]);
            }
        }
    // f2 = fx + Wfh·h2
#pragma unroll
    for (int i = 0; i < 2; ++i)
#pragma unroll
        for (int jj = 0; jj < 2; ++jj) acc[i][jj] = fx[i][jj];
    mfma4k<12>(sA, lrow, lquad, bbB, acc);
    SB();
    load8<2, 1>(bfbase, w, bbB);                // o-gate h B
    SB();
    // fold f2: cc += sigm(f2) * c2
#pragma unroll
    for (int i = 0; i < 2; ++i)
#pragma unroll
        for (int jj = 0; jj < 2; ++jj) {
            const int j = w * 32 + jj * 16 + lrow;
#pragma unroll
            for (int r = 0; r < 4; ++r) {
                const int m = i * 16 + lquad * 4 + r;
                cc[i][jj][r] += sigm(acc[i][jj][r] + bias[3][jj]) * bf2f(sCT[(2 * m + 1) * 136 + j]);
            }
        }
    ZACC();
    mfma4k<0>(sA, lrow, lquad, bbA, acc);
    mfma4k<4>(sA, lrow, lquad, bbB, acc);
    SB();
    // fold o: hh = sigm(o) * tanh(cc)
#pragma unroll
    for (int i = 0; i < 2; ++i)
#pragma unroll
        for (int jj = 0; jj < 2; ++jj)
#pragma unroll
            for (int r = 0; r < 4; ++r)
                hh[i][jj][r] = sigm(acc[i][jj][r] + bias[2][jj]) * fast_tanh(cc[i][jj][r]);
#undef ZACC

    __syncthreads();   // all sCT child reads done

    // ---- write c (rows 0..31) / h (rows 32..63) tiles into sCT ----
#pragma unroll
    for (int i = 0; i < 2; ++i)
#pragma unroll
        for (int jj = 0; jj < 2; ++jj) {
            const int j = w * 32 + jj * 16 + lrow;
#pragma unroll
            for (int r = 0; r < 4; ++r) {
                const int m = i * 16 + lquad * 4 + r;
                sCT[m * 136 + j] = f2bf(cc[i][jj][r]);
                sCT[(32 + m) * 136 + j] = f2bf(hh[i][jj][r]);
            }
        }
    __syncthreads();

    // ---- coalesced flush ----
#pragma unroll
    for (int q = 0; q < 4; ++q) {
        int ci = t + 256 * q;
        int row = ci >> 4;
        int c8 = (ci & 15) * 8;
        int m = row & 31;
        if (m0 + m < nm) {
            bf16raw* dst = (row < 32) ? c_all : h_all;
            *(short8*)(dst + ((long)off + m0 + m) * 128 + c8) = *(const short8*)&sCT[row * 136 + c8];
        }
    }

    // ---- fused logits: wave 0, one MFMA pass vs WoutFrag (layout r13-validated) ----
    if (w == 0) {
        f32x4 lacc[2];
        lacc[0] = (f32x4){0.f, 0.f, 0.f, 0.f};
        lacc[1] = (f32x4){0.f, 0.f, 0.f, 0.f};
#pragma unroll
        for (int kt = 0; kt < 4; ++kt) {
            bf16x8 bfr = *(const bf16x8*)(WoutFrag + (long)((kt * 64 + lane) * 8));
#pragma unroll
            for (int i = 0; i < 2; ++i) {
                bf16x8 af = *(const bf16x8*)&sCT[(32 + i * 16 + lrow) * 136 + kt * 32 + lquad * 8];
                lacc[i] = __builtin_amdgcn_mfma_f32_16x16x32_bf16(af, bfr, lacc[i], 0, 0, 0);
            }
        }
        if (lrow < 5) {
            const float bl = bout[lrow];
#pragma unroll
            for (int i = 0; i < 2; ++i)
#pragma unroll
                for (int r = 0; r < 4; ++r)
                    sLg[(i * 16 + lquad * 4 + r) * 5 + lrow] = lacc[i][r] + bl;
        }
    }
    __syncthreads();

    // ---- lse + loss per node (32 threads) ----
    if (t < 32 && m0 + t < nm) {
        const long g = (long)off + m0 + t;
        float lgv[5], mx = -1e30f;
#pragma unroll
        for (int l = 0; l < 5; ++l) {
            lgv[l] = sLg[t * 5 + l];
            mx = fmaxf(mx, lgv[l]);
        }
        float se = 0.f;
#pragma unroll
        for (int l = 0; l < 5; ++l) se += __expf(lgv[l] - mx);
        float lse = __logf(se) + mx;
        float lossNode = lse - lgv[labels[g]];
        if (leafkids) {
            const float* lv1 = lossv6 + (long)words[2 * g + 1] * 6;
            const float* lv2 = lossv6 + (long)words[2 * g + 2] * 6;
            lossNode += (lv1[5] - lv1[labels[2 * g + 1]])
                      + (lv2[5] - lv2[labels[2 * g + 2]]);
        }
        atomicAdd(&partials[(int)(g & 1023)], lossNode);
        if (isroot && g == 0) {
#pragma unroll
            for (int l = 0; l < 5; ++l) out[l] = lgv[l] - lse;
        }
    }
}

__global__ __launch_bounds__(256) void k3_reduce(const float* __restrict__ partials,
                                                 float* __restrict__ out)
{
    const int t = threadIdx.x;
    float s = 0.f;
    for (int i = t; i < 1024; i += 256) s += partials[i];
#pragma unroll
    for (int d = 32; d > 0; d >>= 1) s += __shfl_down(s, d);
    __shared__ float red[4];
    if ((t & 63) == 0) red[t >> 6] = s;
    __syncthreads();
    if (t == 0) out[5] = red[0] + red[1] + red[2] + red[3];
}

// ---------------------------------------------------------------------------
extern "C" void kernel_launch(void* const* d_in, const int* in_sizes, int n_in,
                              void* d_out, int out_size, void* d_ws, size_t ws_size,
                              hipStream_t stream)
{
    const float* embeds = (const float*)d_in[0];
    const int* words = (const int*)d_in[1];
    const int* labels = (const int*)d_in[2];
    const float* Wix = (const float*)d_in[5],  *bix  = (const float*)d_in[6];
    const float* Wih = (const float*)d_in[7],  *bih  = (const float*)d_in[8];
    const float* Wfx = (const float*)d_in[9],  *bfx  = (const float*)d_in[10];
    const float* Wfh = (const float*)d_in[11], *bfh  = (const float*)d_in[12];
    const float* Wox = (const float*)d_in[13], *box_ = (const float*)d_in[14];
    const float* Woh = (const float*)d_in[15], *boh  = (const float*)d_in[16];
    const float* Wux = (const float*)d_in[17], *bux  = (const float*)d_in[18];
    const float* Wuh = (const float*)d_in[19], *buh  = (const float*)d_in[20];
    const float* Wout = (const float*)d_in[21], *bout = (const float*)d_in[22];
    float* out = (float*)d_out;

    char* ws = (char*)d_ws;
    const size_t treeElems = (size_t)NINT * 128;
    bf16raw* h_all = (bf16raw*)ws;
    bf16raw* c_all = h_all + treeElems;
    bf16raw* embeds_bf = c_all + treeElems;
    bf16raw* Bfrag = embeds_bf + (size_t)NVOCAB * 128;
    bf16raw* WoutFrag = Bfrag + 4 * 8 * KTS * 512;       // padded dedup B, then WoutT frag
    bf16raw* hc_leaf = WoutFrag + 4 * 64 * 8;
    float* lossv6 = (float*)(hc_leaf + (size_t)NVOCAB * 256);
    float* bias_cat = lossv6 + (size_t)NVOCAB * 6;
    float* partials = bias_cat + 512;

    k_prep_embeds<<<(NVOCAB * 128 / 4 + 255) / 256, 256, 0, stream>>>(
        embeds, embeds_bf, NVOCAB * 128 / 4);
    k_prep_bcat<<<528, 128, 0, stream>>>(Wix, bix, Wih, bih, Wfx, bfx, Wfh, bfh,
                                         Wox, box_, Woh, boh, Wux, bux, Wuh, buh,
                                         Wout, Bfrag, WoutFrag, bias_cat);
    hipMemsetAsync(partials, 0, 1024 * sizeof(float), stream);

    k_leafpre<<<(NVOCAB + 63) / 64, 256, 0, stream>>>(
        embeds_bf, Bfrag, bias_cat, Wout, bout, hc_leaf, lossv6, NVOCAB);

    for (int l = DEPTH - 2; l >= 0; --l) {
        const int n = 1 << l;
        k_level32<<<dim3((n + 31) / 32), 256, 0, stream>>>(
            embeds_bf, words, labels, h_all, c_all, hc_leaf, lossv6,
            Bfrag, WoutFrag, bias_cat, bout, partials, out,
            n - 1, n, (l == DEPTH - 2) ? 1 : 0, (l == 0) ? 1 : 0);
    }

    k3_reduce<<<1, 256, 0, stream>>>(partials, out);
}

// Round 15
// 366.458 us; speedup vs baseline: 1.6786x; 1.0135x over previous
//
#include <hip/hip_runtime.h>
#include <math.h>

#define DEPTH 18
#define NINT ((1 << (DEPTH - 1)) - 1)      // internal nodes = 131071
#define LEAF_OFF ((1 << (DEPTH - 2)) - 1)  // first level-16 node = 65535
#define NVOCAB 50000
#define SAW 520                             // sA row stride: [x|hs|h1|h2] + pad
#define KTS 9                               // Bfrag ktile stride (8 used + 1 pad; kills pow2 aliasing — r10 A/B: 70->55us)
#define NEMB (NVOCAB * 128 / 4 / 256)       // 6250 embed-convert blocks

typedef unsigned short bf16raw;
typedef __bf16 bf16x8 __attribute__((ext_vector_type(8)));
typedef float f32x4 __attribute__((ext_vector_type(4)));
typedef short short8 __attribute__((ext_vector_type(8)));

__device__ __forceinline__ float sigm(float x) { return 1.0f / (1.0f + __expf(-x)); }
// NaN-safe fast tanh (saturates correctly at +-inf).
__device__ __forceinline__ float fast_tanh(float x) {
    float t = __expf(2.0f * x);
    return 1.0f - 2.0f / (t + 1.0f);
}

__device__ __forceinline__ float bf2f(bf16raw u) {
    union { unsigned int i; float f; } v;
    v.i = ((unsigned int)u) << 16;
    return v.f;
}
__device__ __forceinline__ bf16raw f2bf(float f) {
    union { float f; unsigned int i; } v;
    v.f = f;
    unsigned int r = v.i + 0x7FFFu + ((v.i >> 16) & 1u);  // RNE
    return (bf16raw)(r >> 16);
}

#define SB() __builtin_amdgcn_sched_barrier(0)

// ---------------------------------------------------------------------------
// k_prep_all: ONE dispatch for all prep (r15: cut 2 dispatch boundaries).
//  blocks [0, NEMB)           : embeds f32 -> bf16
//  blocks [NEMB, NEMB+528)    : Bfrag (fragment-linear dedup B) / WoutFrag
//  block  NEMB+528            : zero partials
// ---------------------------------------------------------------------------
__global__ __launch_bounds__(256) void k_prep_all(
    const float* __restrict__ embeds,
    const float* __restrict__ Wix, const float* __restrict__ bix,
    const float* __restrict__ Wih, const float* __restrict__ bih,
    const float* __restrict__ Wfx, const float* __restrict__ bfx,
    const float* __restrict__ Wfh, const float* __restrict__ bfh,
    const float* __restrict__ Wox, const float* __restrict__ box_,
    const float* __restrict__ Woh, const float* __restrict__ boh,
    const float* __restrict__ Wux, const float* __restrict__ bux,
    const float* __restrict__ Wuh, const float* __restrict__ buh,
    const float* __restrict__ Wout,
    bf16raw* __restrict__ embeds_bf,
    bf16raw* __restrict__ Bfrag, bf16raw* __restrict__ WoutFrag,
    float* __restrict__ bias_cat, float* __restrict__ partials)
{
    const int bid = blockIdx.x;
    const int t = threadIdx.x;
    if (bid < NEMB) {
        const int i = bid * 256 + t;
        float4 v = ((const float4*)embeds)[i];
        ushort4 o;
        o.x = f2bf(v.x); o.y = f2bf(v.y); o.z = f2bf(v.z); o.w = f2bf(v.w);
        ((ushort4*)embeds_bf)[i] = o;
        return;
    }
    if (bid == NEMB + 528) {
#pragma unroll
        for (int s = 0; s < 4; ++s) partials[t + 256 * s] = 0.f;
        return;
    }
    const int j = bid - NEMB;        // 0..527
    if (j >= 512) {
        const int col = j - 512;     // 0..15 WoutFrag col
        for (int k = t; k < 128; k += 256) {
            float v = (col < 5) ? Wout[col * 128 + k] : 0.f;
            WoutFrag[((k >> 5) * 64 + ((k >> 3) & 3) * 16 + col) * 8 + (k & 7)] = f2bf(v);
        }
        return;
    }
    const int gate = j >> 7, jj = j & 127;
    const float *Wx, *Wh, *bx, *bh;
    switch (gate) {
        case 0: Wx = Wix; Wh = Wih; bx = bix;  bh = bih; break;
        case 1: Wx = Wux; Wh = Wuh; bx = bux;  bh = buh; break;
        case 2: Wx = Wox; Wh = Woh; bx = box_; bh = boh; break;
        default: Wx = Wfx; Wh = Wfh; bx = bfx; bh = bfh; break;
    }
    const int coltile = (j >> 4) & 7, lr = j & 15;
    for (int k = t; k < 256; k += 256) {
        float v = (k < 128) ? Wx[jj * 128 + k] : Wh[jj * 128 + (k - 128)];
        const int idx = (((gate * 8 + coltile) * KTS + (k >> 5)) * 64
                         + ((k >> 3) & 3) * 16 + lr) * 8 + (k & 7);
        Bfrag[idx] = f2bf(v);
    }
    if (t == 0) bias_cat[j] = bx[jj] + bh[jj];
}

// ---------------------------------------------------------------------------
// k_leafpre burst helpers (64-row variant: acc[2][4], x-part ktiles 0..3).
// ---------------------------------------------------------------------------
template<int CB>
__device__ __forceinline__ void lp_burst(const bf16raw* __restrict__ bfbase, int wcol,
                                         bf16x8 (&bb)[16])
{
#pragma unroll
    for (int kt = 0; kt < 4; ++kt)
#pragma unroll
        for (int j = 0; j < 4; ++j)
            bb[kt * 4 + j] = *(const bf16x8*)(bfbase +
                    (long)(((CB * 8 + (wcol >> 4) + j) * KTS + kt) * 512));
}

__device__ __forceinline__ void lp_mfma_all(const bf16raw* __restrict__ sA, int wrow,
                                            int lrow, int lquad,
                                            bf16x8 (&bb)[16], f32x4 (&acc)[2][4])
{
#pragma unroll
    for (int kt = 0; kt < 4; ++kt) {
        bf16x8 af[2];
#pragma unroll
        for (int i = 0; i < 2; ++i)
            af[i] = *(const bf16x8*)&sA[(wrow + i * 16 + lrow) * 136 + kt * 32 + lquad * 8];
#pragma unroll
        for (int i = 0; i < 2; ++i)
#pragma unroll
            for (int j = 0; j < 4; ++j)
                acc[i][j] = __builtin_amdgcn_mfma_f32_16x16x32_bf16(af[i], bb[kt * 4 + j], acc[i][j], 0, 0, 0);
    }
}

template<int CB>
__device__ __forceinline__ void lp_rungemm(const bf16raw* __restrict__ sA,
                                           const bf16raw* __restrict__ bfbase,
                                           int wrow, int wcol, int lrow, int lquad,
                                           f32x4 (&acc)[2][4])
{
#pragma unroll
    for (int i = 0; i < 2; i++)
#pragma unroll
        for (int j = 0; j < 4; j++) acc[i][j] = (f32x4){0.f, 0.f, 0.f, 0.f};
    bf16x8 bb[16];
    lp_burst<CB>(bfbase, wcol, bb);
    SB();
    lp_mfma_all(sA, wrow, lrow, lquad, bb, acc);
}

// ---------------------------------------------------------------------------
// k_level half-burst helpers.  Wave w: coltiles w*2, w*2+1.
// ---------------------------------------------------------------------------
template<int G, int H>
__device__ __forceinline__ void load8(const bf16raw* __restrict__ bfbase, int w,
                                      bf16x8 (&bb)[8])
{
#pragma unroll
    for (int kt2 = 0; kt2 < 4; ++kt2)
#pragma unroll
        for (int jj = 0; jj < 2; ++jj)
            bb[kt2 * 2 + jj] = *(const bf16x8*)(bfbase +
                    (long)(((G * 8 + w * 2 + jj) * KTS + H * 4 + kt2) * 512));
}

// 4-ktile MFMA group from A-ktile base AB (x=0, hs=4, h1=8, h2=12).
template<int AB>
__device__ __forceinline__ void mfma4k(const bf16raw* __restrict__ sA, int lrow, int lquad,
                                       bf16x8 (&bb)[8], f32x4 (&acc)[2][2])
{
#pragma unroll
    for (int kt2 = 0; kt2 < 4; ++kt2) {
        bf16x8 af[2];
#pragma unroll
        for (int i = 0; i < 2; ++i)
            af[i] = *(const bf16x8*)&sA[(i * 16 + lrow) * SAW + (AB + kt2) * 32 + lquad * 8];
#pragma unroll
        for (int jj = 0; jj < 2; ++jj)
#pragma unroll
            for (int i = 0; i < 2; ++i)
                acc[i][jj] = __builtin_amdgcn_mfma_f32_16x16x32_bf16(af[i], bb[kt2 * 2 + jj], acc[i][jj], 0, 0, 0);
    }
}

// ---------------------------------------------------------------------------
// k_leafpre: per-vocab leaf tables (h, c, logits, lse).  64 rows/block.
// r15: scalar logits GEMV (160 FMA + shuffles per thread-pair) replaced by
// MFMA vs WoutFrag (4 MFMAs/wave; layout validated r13/r14); sWout staging
// removed.  LDS 37.3 -> 36.1KB.
// ---------------------------------------------------------------------------
__global__ __launch_bounds__(256, 3) void k_leafpre(
    const bf16raw* __restrict__ embeds_bf,
    const bf16raw* __restrict__ Bfrag, const float* __restrict__ bias_cat,
    const bf16raw* __restrict__ WoutFrag, const float* __restrict__ bout,
    bf16raw* __restrict__ hc_leaf, float* __restrict__ lossv6, int nvtot)
{
    const int vbase = blockIdx.x * 64;
    int nv = nvtot - vbase;
    if (nv > 64) nv = 64;
    if (nv <= 0) return;

    __shared__ __align__(16) bf16raw sA[64 * 136];
    __shared__ __align__(16) bf16raw sT[64 * 136];
    __shared__ float sLg[64 * 5];

    const int t = threadIdx.x;

    // ---- stage A: 4 threads/row x 32 elems ----
    {
        const int row = t >> 2;              // 0..63
        const int co = (t & 3) * 32;
        const int arow = (row < nv) ? row : 0;
        const bf16raw* ax = embeds_bf + (long)(vbase + arow) * 128;
        *(short8*)&sA[row * 136 + co]      = *(const short8*)(ax + co);
        *(short8*)&sA[row * 136 + co + 8]  = *(const short8*)(ax + co + 8);
        *(short8*)&sA[row * 136 + co + 16] = *(const short8*)(ax + co + 16);
        *(short8*)&sA[row * 136 + co + 24] = *(const short8*)(ax + co + 24);
    }

    const int lane = t & 63;
    const int w = t >> 6;
    const int wrow = (w & 1) * 32;
    const int wcol = (w >> 1) * 64;
    const int lrow = lane & 15;
    const int lquad = lane >> 4;

    __syncthreads();

    const bf16raw* bfbase = Bfrag + (long)lane * 8;

    float tval[2][4][4];
    f32x4 acc[2][4];

    // ---- i gate ----
    lp_rungemm<0>(sA, bfbase, wrow, wcol, lrow, lquad, acc);
#pragma unroll
    for (int i = 0; i < 2; i++)
#pragma unroll
        for (int jj = 0; jj < 4; jj++) {
            const float b = bias_cat[wcol + jj * 16 + lrow];
#pragma unroll
            for (int r = 0; r < 4; r++) tval[i][jj][r] = sigm(acc[i][jj][r] + b);
        }
    // ---- u gate: tval = c = i*u ----
    lp_rungemm<1>(sA, bfbase, wrow, wcol, lrow, lquad, acc);
#pragma unroll
    for (int i = 0; i < 2; i++)
#pragma unroll
        for (int jj = 0; jj < 4; jj++) {
            const float b = bias_cat[128 + wcol + jj * 16 + lrow];
#pragma unroll
            for (int r = 0; r < 4; r++) tval[i][jj][r] *= fast_tanh(acc[i][jj][r] + b);
        }
    // write c tile, keep tanh(c) in regs
#pragma unroll
    for (int i = 0; i < 2; i++)
#pragma unroll
        for (int jj = 0; jj < 4; jj++)
#pragma unroll
            for (int r = 0; r < 4; r++) {
                const int m = wrow + i * 16 + lquad * 4 + r;
                const int j = wcol + jj * 16 + lrow;
                sT[m * 136 + j] = f2bf(tval[i][jj][r]);
            }
#pragma unroll
    for (int i = 0; i < 2; i++)
#pragma unroll
        for (int jj = 0; jj < 4; jj++)
#pragma unroll
            for (int r = 0; r < 4; r++) tval[i][jj][r] = fast_tanh(tval[i][jj][r]);
    __syncthreads();
    // flush c
#pragma unroll
    for (int s = 0; s < 4; ++s) {
        int ci = t + 256 * s;
        int row = ci >> 4, c8 = (ci & 15) * 8;
        if (row < nv)
            *(short8*)(hc_leaf + (long)(vbase + row) * 256 + 128 + c8) = *(const short8*)&sT[row * 136 + c8];
    }
    // ---- o gate: h = sigm(o)*tanh(c) ----
    lp_rungemm<2>(sA, bfbase, wrow, wcol, lrow, lquad, acc);
    __syncthreads();
#pragma unroll
    for (int i = 0; i < 2; i++)
#pragma unroll
        for (int jj = 0; jj < 4; jj++) {
            const float b = bias_cat[256 + wcol + jj * 16 + lrow];
#pragma unroll
            for (int r = 0; r < 4; r++) {
                const int m = wrow + i * 16 + lquad * 4 + r;
                const int j = wcol + jj * 16 + lrow;
                sT[m * 136 + j] = f2bf(sigm(acc[i][jj][r] + b) * tval[i][jj][r]);
            }
        }
    __syncthreads();
    // flush h
#pragma unroll
    for (int s = 0; s < 4; ++s) {
        int ci = t + 256 * s;
        int row = ci >> 4, c8 = (ci & 15) * 8;
        if (row < nv)
            *(short8*)(hc_leaf + (long)(vbase + row) * 256 + c8) = *(const short8*)&sT[row * 136 + c8];
    }
    // ---- logits via MFMA: wave w handles rows w*16..w*16+16 ----
    {
        f32x4 lacc = (f32x4){0.f, 0.f, 0.f, 0.f};
#pragma unroll
        for (int kt = 0; kt < 4; ++kt) {
            bf16x8 bfr = *(const bf16x8*)(WoutFrag + (long)((kt * 64 + lane) * 8));
            bf16x8 af = *(const bf16x8*)&sT[(w * 16 + lrow) * 136 + kt * 32 + lquad * 8];
            lacc = __builtin_amdgcn_mfma_f32_16x16x32_bf16(af, bfr, lacc, 0, 0, 0);
        }
        if (lrow < 5) {
            const float bl = bout[lrow];
#pragma unroll
            for (int r = 0; r < 4; ++r)
                sLg[(w * 16 + lquad * 4 + r) * 5 + lrow] = lacc[r] + bl;
        }
    }
    __syncthreads();
    // ---- lse per row (64 threads) ----
    if (t < 64 && t < nv) {
        float lg[5], mx = -1e30f;
#pragma unroll
        for (int l = 0; l < 5; l++) {
            lg[l] = sLg[t * 5 + l];
            mx = fmaxf(mx, lg[l]);
        }
        float se = 0.f;
#pragma unroll
        for (int l = 0; l < 5; l++) se += __expf(lg[l] - mx);
        float lse = __logf(se) + mx;
        float* dst = lossv6 + (long)(vbase + t) * 6;
#pragma unroll
        for (int l = 0; l < 5; l++) dst[l] = lg[l];
        dst[5] = lse;
    }
}

// ---------------------------------------------------------------------------
// k_level32 (r14 body; r15 adds root-fused final reduction):
//  - LDS children staging (sCT), (256,3), fx-sharing, fused-loss epilogue.
//  - isroot (l=0, single block): skip own atomicAdd, sum partials + own
//    loss -> out[5]: k3_reduce dispatch eliminated.
// ---------------------------------------------------------------------------
__global__ __launch_bounds__(256, 3) void k_level32(
    const bf16raw* __restrict__ embeds_bf, const int* __restrict__ words,
    const int* __restrict__ labels,
    bf16raw* __restrict__ h_all, bf16raw* __restrict__ c_all,
    const bf16raw* __restrict__ hc_leaf, const float* __restrict__ lossv6,
    const bf16raw* __restrict__ Bfrag, const bf16raw* __restrict__ WoutFrag,
    const float* __restrict__ bias_cat, const float* __restrict__ bout,
    float* __restrict__ partials, float* __restrict__ out,
    int off, int nm, int leafkids, int isroot)
{
    __shared__ __align__(16) bf16raw sA[32 * SAW];
    __shared__ __align__(16) bf16raw sCT[64 * 136];
    __shared__ float sLg[168];   // [0..159] logits; [160..163] red; [164] root loss

    const int t = threadIdx.x;
    const int m0 = blockIdx.x * 32;

    // ---- stage A tile [x|hs|h1|h2]: 8 threads/row ----
    {
        const int row = t >> 3;
        const int co = (t & 7) * 8;
        int mm = m0 + row; if (mm >= nm) mm = nm - 1;
        const long g = (long)off + mm;
        const bf16raw* px = embeds_bf + (long)words[g] * 128;
        const bf16raw *p1, *p2;
        if (leafkids) {
            p1 = hc_leaf + (long)words[2 * g + 1] * 256;
            p2 = hc_leaf + (long)words[2 * g + 2] * 256;
        } else {
            p1 = h_all + (2 * g + 1) * 128;
            p2 = h_all + (2 * g + 2) * 128;
        }
        short8 vx0 = *(const short8*)(px + co);
        short8 vx1 = *(const short8*)(px + 64 + co);
        short8 h10 = *(const short8*)(p1 + co);
        short8 h11 = *(const short8*)(p1 + 64 + co);
        short8 h20 = *(const short8*)(p2 + co);
        short8 h21 = *(const short8*)(p2 + 64 + co);
        short8 hs0, hs1;
#pragma unroll
        for (int e = 0; e < 8; ++e) {
            hs0[e] = (short)f2bf(bf2f((bf16raw)(unsigned short)h10[e]) +
                                 bf2f((bf16raw)(unsigned short)h20[e]));
            hs1[e] = (short)f2bf(bf2f((bf16raw)(unsigned short)h11[e]) +
                                 bf2f((bf16raw)(unsigned short)h21[e]));
        }
        *(short8*)&sA[row * SAW + co]        = vx0;
        *(short8*)&sA[row * SAW + 64 + co]   = vx1;
        *(short8*)&sA[row * SAW + 128 + co]  = hs0;
        *(short8*)&sA[row * SAW + 192 + co]  = hs1;
        *(short8*)&sA[row * SAW + 256 + co]  = h10;
        *(short8*)&sA[row * SAW + 320 + co]  = h11;
        *(short8*)&sA[row * SAW + 384 + co]  = h20;
        *(short8*)&sA[row * SAW + 448 + co]  = h21;
    }
    // ---- stage children c: slot = 2*mlocal + childIdx ----
    {
        const int slot = t >> 2;
        const int cc8 = (t & 3) * 8;
        int mm = m0 + (slot >> 1); if (mm >= nm) mm = nm - 1;
        const long g = (long)off + mm;
        const long cg = 2 * g + 1 + (slot & 1);
        const bf16raw* pc = leafkids ? (hc_leaf + (long)words[cg] * 256 + 128)
                                     : (c_all + cg * 128);
#pragma unroll
        for (int s = 0; s < 4; ++s)
            *(short8*)&sCT[slot * 136 + s * 32 + cc8] = *(const short8*)(pc + s * 32 + cc8);
    }

    const int lane = t & 63;
    const int w = t >> 6;
    const int lrow = lane & 15;
    const int lquad = lane >> 4;

    // bias preload (gate order 0=i,1=u,2=o,3=f)
    float bias[4][2];
#pragma unroll
    for (int g = 0; g < 4; ++g)
#pragma unroll
        for (int jj = 0; jj < 2; ++jj)
            bias[g][jj] = bias_cat[g * 128 + w * 32 + jj * 16 + lrow];

    __syncthreads();   // A tile + children staged

    const bf16raw* bfbase = Bfrag + (long)lane * 8;

    f32x4 acc[2][2];
    f32x4 fx[2][2];      // Wfx·x stash (shared by f1/f2)
    float si[2][2][4];   // sigm(i) stash
    float cc[2][2][4];   // running c
    float hh[2][2][4];   // final h
    bf16x8 bbA[8], bbB[8];

#define ZACC() { _Pragma("unroll") for (int i_ = 0; i_ < 2; ++i_) \
                 _Pragma("unroll") for (int j_ = 0; j_ < 2; ++j_) \
                     acc[i_][j_] = (f32x4){0.f, 0.f, 0.f, 0.f}; }

    load8<0, 0>(bfbase, w, bbA);
    load8<0, 1>(bfbase, w, bbB);
    SB();
    ZACC();
    mfma4k<0>(sA, lrow, lquad, bbA, acc); SB();
    load8<1, 0>(bfbase, w, bbA); SB();
    mfma4k<4>(sA, lrow, lquad, bbB, acc); SB();
    load8<1, 1>(bfbase, w, bbB); SB();
    // fold i
#pragma unroll
    for (int i = 0; i < 2; ++i)
#pragma unroll
        for (int jj = 0; jj < 2; ++jj)
#pragma unroll
            for (int r = 0; r < 4; ++r)
                si[i][jj][r] = sigm(acc[i][jj][r] + bias[0][jj]);
    ZACC();
    mfma4k<0>(sA, lrow, lquad, bbA, acc); SB();
    load8<3, 0>(bfbase, w, bbA); SB();          // f-gate x-part B
    mfma4k<4>(sA, lrow, lquad, bbB, acc); SB();
    load8<3, 1>(bfbase, w, bbB); SB();          // f-gate h-part B
    // fold u: cc = sigm(i) * tanh(u)
#pragma unroll
    for (int i = 0; i < 2; ++i)
#pragma unroll
        for (int jj = 0; jj < 2; ++jj)
#pragma unroll
            for (int r = 0; r < 4; ++r)
                cc[i][jj][r] = si[i][jj][r] * fast_tanh(acc[i][jj][r] + bias[1][jj]);
    // fx = Wfx·x (once)
    ZACC();
    mfma4k<0>(sA, lrow, lquad, bbA, acc);
    SB();
#pragma unroll
    for (int i = 0; i < 2; ++i)
#pragma unroll
        for (int jj = 0; jj < 2; ++jj) fx[i][jj] = acc[i][jj];
    // f1 = fx + Wfh·h1
    mfma4k<8>(sA, lrow, lquad, bbB, acc);
    SB();
    load8<2, 0>(bfbase, w, bbA);                // o-gate x B (overlaps fold)
    SB();
    // fold f1: cc += sigm(f1) * c1
#pragma unroll
    for (int i = 0; i < 2; ++i)
#pragma unroll
        for (int jj = 0; jj < 2; ++jj) {
            const int j = w * 32 + jj * 16 + lrow;
#pragma unroll
            for (int r = 0; r < 4; ++r) {
                const int m = i * 16 + lquad * 4 + r;
                cc[i][jj][r] += sigm(acc[i][jj][r] + bias[3][jj]) * bf2f(sCT[(2 * m) * 136 + j]);
            }
        }
    // f2 = fx + Wfh·h2
#pragma unroll
    for (int i = 0; i < 2; ++i)
#pragma unroll
        for (int jj = 0; jj < 2; ++jj) acc[i][jj] = fx[i][jj];
    mfma4k<12>(sA, lrow, lquad, bbB, acc);
    SB();
    load8<2, 1>(bfbase, w, bbB);                // o-gate h B
    SB();
    // fold f2: cc += sigm(f2) * c2
#pragma unroll
    for (int i = 0; i < 2; ++i)
#pragma unroll
        for (int jj = 0; jj < 2; ++jj) {
            const int j = w * 32 + jj * 16 + lrow;
#pragma unroll
            for (int r = 0; r < 4; ++r) {
                const int m = i * 16 + lquad * 4 + r;
                cc[i][jj][r] += sigm(acc[i][jj][r] + bias[3][jj]) * bf2f(sCT[(2 * m + 1) * 136 + j]);
            }
        }
    ZACC();
    mfma4k<0>(sA, lrow, lquad, bbA, acc);
    mfma4k<4>(sA, lrow, lquad, bbB, acc);
    SB();
    // fold o: hh = sigm(o) * tanh(cc)
#pragma unroll
    for (int i = 0; i < 2; ++i)
#pragma unroll
        for (int jj = 0; jj < 2; ++jj)
#pragma unroll
            for (int r = 0; r < 4; ++r)
                hh[i][jj][r] = sigm(acc[i][jj][r] + bias[2][jj]) * fast_tanh(cc[i][jj][r]);
#undef ZACC

    __syncthreads();   // all sCT child reads done

    // ---- write c (rows 0..31) / h (rows 32..63) tiles into sCT ----
#pragma unroll
    for (int i = 0; i < 2; ++i)
#pragma unroll
        for (int jj = 0; jj < 2; ++jj) {
            const int j = w * 32 + jj * 16 + lrow;
#pragma unroll
            for (int r = 0; r < 4; ++r) {
                const int m = i * 16 + lquad * 4 + r;
                sCT[m * 136 + j] = f2bf(cc[i][jj][r]);
                sCT[(32 + m) * 136 + j] = f2bf(hh[i][jj][r]);
            }
        }
    __syncthreads();

    // ---- coalesced flush ----
#pragma unroll
    for (int q = 0; q < 4; ++q) {
        int ci = t + 256 * q;
        int row = ci >> 4;
        int c8 = (ci & 15) * 8;
        int m = row & 31;
        if (m0 + m < nm) {
            bf16raw* dst = (row < 32) ? c_all : h_all;
            *(short8*)(dst + ((long)off + m0 + m) * 128 + c8) = *(const short8*)&sCT[row * 136 + c8];
        }
    }

    // ---- fused logits: wave 0, one MFMA pass vs WoutFrag ----
    if (w == 0) {
        f32x4 lacc[2];
        lacc[0] = (f32x4){0.f, 0.f, 0.f, 0.f};
        lacc[1] = (f32x4){0.f, 0.f, 0.f, 0.f};
#pragma unroll
        for (int kt = 0; kt < 4; ++kt) {
            bf16x8 bfr = *(const bf16x8*)(WoutFrag + (long)((kt * 64 + lane) * 8));
#pragma unroll
            for (int i = 0; i < 2; ++i) {
                bf16x8 af = *(const bf16x8*)&sCT[(32 + i * 16 + lrow) * 136 + kt * 32 + lquad * 8];
                lacc[i] = __builtin_amdgcn_mfma_f32_16x16x32_bf16(af, bfr, lacc[i], 0, 0, 0);
            }
        }
        if (lrow < 5) {
            const float bl = bout[lrow];
#pragma unroll
            for (int i = 0; i < 2; ++i)
#pragma unroll
                for (int r = 0; r < 4; ++r)
                    sLg[(i * 16 + lquad * 4 + r) * 5 + lrow] = lacc[i][r] + bl;
        }
    }
    __syncthreads();

    // ---- lse + loss per node (32 threads) ----
    if (t < 32 && m0 + t < nm) {
        const long g = (long)off + m0 + t;
        float lgv[5], mx = -1e30f;
#pragma unroll
        for (int l = 0; l < 5; ++l) {
            lgv[l] = sLg[t * 5 + l];
            mx = fmaxf(mx, lgv[l]);
        }
        float se = 0.f;
#pragma unroll
        for (int l = 0; l < 5; ++l) se += __expf(lgv[l] - mx);
        float lse = __logf(se) + mx;
        float lossNode = lse - lgv[labels[g]];
        if (leafkids) {
            const float* lv1 = lossv6 + (long)words[2 * g + 1] * 6;
            const float* lv2 = lossv6 + (long)words[2 * g + 2] * 6;
            lossNode += (lv1[5] - lv1[labels[2 * g + 1]])
                      + (lv2[5] - lv2[labels[2 * g + 2]]);
        }
        if (isroot) {
            sLg[164] = lossNode;   // root keeps its term local (t==0 only valid)
#pragma unroll
            for (int l = 0; l < 5; ++l) out[l] = lgv[l] - lse;
        } else {
            atomicAdd(&partials[(int)(g & 1023)], lossNode);
        }
    }

    // ---- root-fused final reduction (l=0 is a single block; all earlier
    //      levels' atomics have drained before this dispatch) ----
    if (isroot) {
        __syncthreads();
        float s = 0.f;
        for (int i2 = t; i2 < 1024; i2 += 256) s += partials[i2];
#pragma unroll
        for (int d = 32; d > 0; d >>= 1) s += __shfl_down(s, d);
        if ((t & 63) == 0) sLg[160 + (t >> 6)] = s;
        __syncthreads();
        if (t == 0)
            out[5] = sLg[160] + sLg[161] + sLg[162] + sLg[163] + sLg[164];
    }
}

// ---------------------------------------------------------------------------
extern "C" void kernel_launch(void* const* d_in, const int* in_sizes, int n_in,
                              void* d_out, int out_size, void* d_ws, size_t ws_size,
                              hipStream_t stream)
{
    const float* embeds = (const float*)d_in[0];
    const int* words = (const int*)d_in[1];
    const int* labels = (const int*)d_in[2];
    const float* Wix = (const float*)d_in[5],  *bix  = (const float*)d_in[6];
    const float* Wih = (const float*)d_in[7],  *bih  = (const float*)d_in[8];
    const float* Wfx = (const float*)d_in[9],  *bfx  = (const float*)d_in[10];
    const float* Wfh = (const float*)d_in[11], *bfh  = (const float*)d_in[12];
    const float* Wox = (const float*)d_in[13], *box_ = (const float*)d_in[14];
    const float* Woh = (const float*)d_in[15], *boh  = (const float*)d_in[16];
    const float* Wux = (const float*)d_in[17], *bux  = (const float*)d_in[18];
    const float* Wuh = (const float*)d_in[19], *buh  = (const float*)d_in[20];
    const float* Wout = (const float*)d_in[21], *bout = (const float*)d_in[22];
    float* out = (float*)d_out;

    char* ws = (char*)d_ws;
    const size_t treeElems = (size_t)NINT * 128;
    bf16raw* h_all = (bf16raw*)ws;
    bf16raw* c_all = h_all + treeElems;
    bf16raw* embeds_bf = c_all + treeElems;
    bf16raw* Bfrag = embeds_bf + (size_t)NVOCAB * 128;
    bf16raw* WoutFrag = Bfrag + 4 * 8 * KTS * 512;       // padded dedup B, then WoutT frag
    bf16raw* hc_leaf = WoutFrag + 4 * 64 * 8;
    float* lossv6 = (float*)(hc_leaf + (size_t)NVOCAB * 256);
    float* bias_cat = lossv6 + (size_t)NVOCAB * 6;
    float* partials = bias_cat + 512;

    k_prep_all<<<NEMB + 528 + 1, 256, 0, stream>>>(
        embeds, Wix, bix, Wih, bih, Wfx, bfx, Wfh, bfh,
        Wox, box_, Woh, boh, Wux, bux, Wuh, buh, Wout,
        embeds_bf, Bfrag, WoutFrag, bias_cat, partials);

    k_leafpre<<<(NVOCAB + 63) / 64, 256, 0, stream>>>(
        embeds_bf, Bfrag, bias_cat, WoutFrag, bout, hc_leaf, lossv6, NVOCAB);

    for (int l = DEPTH - 2; l >= 0; --l) {
        const int n = 1 << l;
        k_level32<<<dim3((n + 31) / 32), 256, 0, stream>>>(
            embeds_bf, words, labels, h_all, c_all, hc_leaf, lossv6,
            Bfrag, WoutFrag, bias_cat, bout, partials, out,
            n - 1, n, (l == DEPTH - 2) ? 1 : 0, (l == 0) ? 1 : 0);
    }
}